// Round 1
// baseline (384.295 us; speedup 1.0000x reference)
//
#include <hip/hip_runtime.h>
#include <hip/hip_bf16.h>

// DAGMM forward, fp32. Pipeline:
//   K0 transpose_k : w2^T (30x60), w8^T (120x60) into d_ws
//   K1 mlp_k       : full AE + estimation net per row -> gamma, zc in d_out
//   K2 stats_k     : column-parallel GMM moment accumulation -> partials in d_ws
//   K3 finalize_k  : reduce partials, mu/cov/Cholesky/log-consts; cov -> d_out
//   K4 energy_k    : per-row triangular solve + logsumexp -> energy in d_out
//
// d_out layout (floats): [energy N][gamma N*10][zc N*4][cov 160]
// d_ws  layout (floats): [w2T 1800][w8T 7200][pad][pp 10*64*16 @9024][consts 160 @19264]

#define TPB 128

__device__ __forceinline__ float fast_tanh(float v) {
    // tanh(x) = 1 - 2/(exp(2x)+1); exp overflow/underflow give correct +-1 limits
    float e = __expf(2.0f * v);
    return 1.0f - __fdividef(2.0f, e + 1.0f);
}

__device__ __forceinline__ float wave_sum(float v) {
    #pragma unroll
    for (int off = 32; off > 0; off >>= 1) v += __shfl_xor(v, off, 64);
    return v;
}

// ---------------- K0: weight transposes ----------------
__global__ __launch_bounds__(256) void transpose_k(
    const float* __restrict__ w2, float* __restrict__ w2t,
    const float* __restrict__ w8, float* __restrict__ w8t) {
    int idx = blockIdx.x * 256 + threadIdx.x;
    if (idx < 1800) {            // w2: (60,30) -> (30,60)
        int i = idx / 30, j = idx % 30;
        w2t[j * 60 + i] = w2[idx];
    }
    for (int t = idx; t < 7200; t += gridDim.x * 256) {   // w8: (60,120) -> (120,60)
        int i = t / 120, j = t % 120;
        w8t[j * 60 + i] = w8[t];
    }
}

// ---------------- K1: the MLP ----------------
__global__ __launch_bounds__(TPB, 4) void mlp_k(
    const float* __restrict__ x,
    const float* __restrict__ w1,  const float* __restrict__ b1,
    const float* __restrict__ b2,
    const float* __restrict__ w3,  const float* __restrict__ b3,
    const float* __restrict__ w4,  const float* __restrict__ b4,
    const float* __restrict__ w5,  const float* __restrict__ b5,
    const float* __restrict__ w6,  const float* __restrict__ b6,
    const float* __restrict__ w7,  const float* __restrict__ b7,
    const float* __restrict__ b8,
    const float* __restrict__ w9,  const float* __restrict__ b9,
    const float* __restrict__ w10, const float* __restrict__ b10,
    const float* __restrict__ w2t, const float* __restrict__ w8t,
    float* __restrict__ g_out, float* __restrict__ z_out) {

    __shared__ float buf[30 * TPB];   // per-thread bounce buffer, slot [v][tid]
    const int tid = threadIdx.x;
    const size_t row = (size_t)blockIdx.x * TPB + tid;

    // ---- L1: 120 -> 60 (i-rolled, stream x from global; w1 native [i][j])
    float h1[60];
    #pragma unroll
    for (int j = 0; j < 60; ++j) h1[j] = b1[j];
    const float4* xr = (const float4*)(x + row * 120);
    #pragma unroll 1
    for (int i0 = 0; i0 < 30; ++i0) {
        float4 xv = xr[i0];
        const float* wr = w1 + i0 * 4 * 60;
        #pragma unroll
        for (int j = 0; j < 60; ++j) h1[j] = fmaf(xv.x, wr[j], h1[j]);
        #pragma unroll
        for (int j = 0; j < 60; ++j) h1[j] = fmaf(xv.y, wr[60 + j], h1[j]);
        #pragma unroll
        for (int j = 0; j < 60; ++j) h1[j] = fmaf(xv.z, wr[120 + j], h1[j]);
        #pragma unroll
        for (int j = 0; j < 60; ++j) h1[j] = fmaf(xv.w, wr[180 + j], h1[j]);
    }
    #pragma unroll
    for (int j = 0; j < 60; ++j) h1[j] = fast_tanh(h1[j]);

    // ---- L2: 60 -> 30 (j-rolled, w2t[j*60+i]; out -> LDS bounce)
    #pragma unroll 2
    for (int j = 0; j < 30; ++j) {
        const float* wr = w2t + j * 60;
        float a0 = b2[j], a1 = 0.0f;
        #pragma unroll
        for (int i = 0; i < 60; i += 2) {
            a0 = fmaf(h1[i],     wr[i],     a0);
            a1 = fmaf(h1[i + 1], wr[i + 1], a1);
        }
        buf[j * TPB + tid] = fast_tanh(a0 + a1);
    }

    // ---- L3: 30 -> 10 (i-rolled from LDS; w3 native)
    float h3[10];
    #pragma unroll
    for (int j = 0; j < 10; ++j) h3[j] = b3[j];
    #pragma unroll 2
    for (int i = 0; i < 30; ++i) {
        float v = buf[i * TPB + tid];
        const float* wr = w3 + i * 10;
        #pragma unroll
        for (int j = 0; j < 10; ++j) h3[j] = fmaf(v, wr[j], h3[j]);
    }
    #pragma unroll
    for (int j = 0; j < 10; ++j) h3[j] = fast_tanh(h3[j]);

    // ---- L4: 10 -> 4 (fully unrolled) -> zc (latent, no activation)
    float zc[4];
    #pragma unroll
    for (int j = 0; j < 4; ++j) zc[j] = b4[j];
    #pragma unroll
    for (int i = 0; i < 10; ++i) {
        #pragma unroll
        for (int j = 0; j < 4; ++j) zc[j] = fmaf(h3[i], w4[i * 4 + j], zc[j]);
    }

    // ---- L5: 4 -> 10 (fully unrolled)
    float h5[10];
    #pragma unroll
    for (int j = 0; j < 10; ++j) h5[j] = b5[j];
    #pragma unroll
    for (int i = 0; i < 4; ++i) {
        #pragma unroll
        for (int j = 0; j < 10; ++j) h5[j] = fmaf(zc[i], w5[i * 10 + j], h5[j]);
    }
    #pragma unroll
    for (int j = 0; j < 10; ++j) h5[j] = fast_tanh(h5[j]);

    // ---- L6: 10 -> 30 (fully unrolled) -> LDS bounce
    float h6[30];
    #pragma unroll
    for (int j = 0; j < 30; ++j) h6[j] = b6[j];
    #pragma unroll
    for (int i = 0; i < 10; ++i) {
        #pragma unroll
        for (int j = 0; j < 30; ++j) h6[j] = fmaf(h5[i], w6[i * 30 + j], h6[j]);
    }
    #pragma unroll
    for (int j = 0; j < 30; ++j) buf[j * TPB + tid] = fast_tanh(h6[j]);

    // ---- L7: 30 -> 60 (i-rolled from LDS; w7 native)
    float h7[60];
    #pragma unroll
    for (int j = 0; j < 60; ++j) h7[j] = b7[j];
    #pragma unroll 2
    for (int i = 0; i < 30; ++i) {
        float v = buf[i * TPB + tid];
        const float* wr = w7 + i * 60;
        #pragma unroll
        for (int j = 0; j < 60; ++j) h7[j] = fmaf(v, wr[j], h7[j]);
    }
    #pragma unroll
    for (int j = 0; j < 60; ++j) h7[j] = fast_tanh(h7[j]);

    // ---- L8 (60->120, linear) fused with L9 (120->10): x_ never materialized
    float z9[10];
    #pragma unroll
    for (int c = 0; c < 10; ++c) z9[c] = b9[c];
    #pragma unroll 2
    for (int j = 0; j < 120; ++j) {
        const float* wr = w8t + j * 60;
        float a0 = b8[j], a1 = 0.0f;
        #pragma unroll
        for (int i = 0; i < 60; i += 2) {
            a0 = fmaf(h7[i],     wr[i],     a0);
            a1 = fmaf(h7[i + 1], wr[i + 1], a1);
        }
        float xj = a0 + a1;
        const float* w9r = w9 + j * 10;
        #pragma unroll
        for (int c = 0; c < 10; ++c) z9[c] = fmaf(xj, w9r[c], z9[c]);
    }
    #pragma unroll
    for (int c = 0; c < 10; ++c) z9[c] = fast_tanh(z9[c]);

    // ---- L10: 10 -> 10 (fully unrolled) + softmax
    float lg[10];
    #pragma unroll
    for (int j = 0; j < 10; ++j) lg[j] = b10[j];
    #pragma unroll
    for (int i = 0; i < 10; ++i) {
        #pragma unroll
        for (int j = 0; j < 10; ++j) lg[j] = fmaf(z9[i], w10[i * 10 + j], lg[j]);
    }
    float mx = lg[0];
    #pragma unroll
    for (int k = 1; k < 10; ++k) mx = fmaxf(mx, lg[k]);
    float g[10];
    float s = 0.0f;
    #pragma unroll
    for (int k = 0; k < 10; ++k) { g[k] = __expf(lg[k] - mx); s += g[k]; }
    float inv = __fdividef(1.0f, s);

    // ---- stores
    float2* gp = (float2*)(g_out + row * 10);
    #pragma unroll
    for (int k = 0; k < 5; ++k) gp[k] = make_float2(g[2 * k] * inv, g[2 * k + 1] * inv);
    *(float4*)(z_out + row * 4) = make_float4(zc[0], zc[1], zc[2], zc[3]);
}

// ---------------- K2: GMM moment accumulation ----------------
// grid = 5 k-pairs x 64 row-chunks; each thread keeps 2x15 register accumulators
__global__ __launch_bounds__(256) void stats_k(
    const float* __restrict__ g_out, const float* __restrict__ z_out,
    float* __restrict__ pp, int N) {
    const int kp = blockIdx.x >> 6;      // 0..4
    const int c  = blockIdx.x & 63;      // 0..63
    const int k0 = kp * 2;
    const int tid = threadIdx.x;
    const int rows_per_chunk = N >> 6;   // N/64
    const int iters = rows_per_chunk >> 8;  // /256
    const int base = c * rows_per_chunk;

    float a0[15], a1[15];
    #pragma unroll
    for (int i = 0; i < 15; ++i) { a0[i] = 0.0f; a1[i] = 0.0f; }

    #pragma unroll 2
    for (int m = 0; m < iters; ++m) {
        int r = base + m * 256 + tid;
        float4 z = *(const float4*)(z_out + (size_t)r * 4);
        float2 g01 = *(const float2*)(g_out + (size_t)r * 10 + k0);
        {
            float gv = g01.x;
            float t0 = gv * z.x, t1 = gv * z.y, t2 = gv * z.z, t3 = gv * z.w;
            a0[0] += gv;
            a0[1] += t0; a0[2] += t1; a0[3] += t2; a0[4] += t3;
            a0[5]  = fmaf(t0, z.x, a0[5]);  a0[6]  = fmaf(t0, z.y, a0[6]);
            a0[7]  = fmaf(t0, z.z, a0[7]);  a0[8]  = fmaf(t0, z.w, a0[8]);
            a0[9]  = fmaf(t1, z.y, a0[9]);  a0[10] = fmaf(t1, z.z, a0[10]);
            a0[11] = fmaf(t1, z.w, a0[11]); a0[12] = fmaf(t2, z.z, a0[12]);
            a0[13] = fmaf(t2, z.w, a0[13]); a0[14] = fmaf(t3, z.w, a0[14]);
        }
        {
            float gv = g01.y;
            float t0 = gv * z.x, t1 = gv * z.y, t2 = gv * z.z, t3 = gv * z.w;
            a1[0] += gv;
            a1[1] += t0; a1[2] += t1; a1[3] += t2; a1[4] += t3;
            a1[5]  = fmaf(t0, z.x, a1[5]);  a1[6]  = fmaf(t0, z.y, a1[6]);
            a1[7]  = fmaf(t0, z.z, a1[7]);  a1[8]  = fmaf(t0, z.w, a1[8]);
            a1[9]  = fmaf(t1, z.y, a1[9]);  a1[10] = fmaf(t1, z.z, a1[10]);
            a1[11] = fmaf(t1, z.w, a1[11]); a1[12] = fmaf(t2, z.z, a1[12]);
            a1[13] = fmaf(t2, z.w, a1[13]); a1[14] = fmaf(t3, z.w, a1[14]);
        }
    }

    #pragma unroll
    for (int i = 0; i < 15; ++i) { a0[i] = wave_sum(a0[i]); a1[i] = wave_sum(a1[i]); }

    __shared__ float wp[4][30];
    const int wave = tid >> 6, lane = tid & 63;
    if (lane == 0) {
        #pragma unroll
        for (int i = 0; i < 15; ++i) { wp[wave][i] = a0[i]; wp[wave][15 + i] = a1[i]; }
    }
    __syncthreads();
    if (tid < 30) {
        float s = wp[0][tid] + wp[1][tid] + wp[2][tid] + wp[3][tid];
        int k = k0 + (tid / 15);
        int i = tid % 15;
        pp[((size_t)k * 64 + c) * 16 + i] = s;
    }
}

// ---------------- K3: finalize GMM params ----------------
__global__ __launch_bounds__(256) void finalize_k(
    const float* __restrict__ pp, float* __restrict__ consts,
    float* __restrict__ cov_out, int N) {
    __shared__ float sums[10][16];
    const int tid = threadIdx.x;
    if (tid < 150) {
        int k = tid / 15, i = tid % 15;
        float s0 = 0.f, s1 = 0.f, s2 = 0.f, s3 = 0.f;
        for (int c = 0; c < 64; c += 4) {
            s0 += pp[((size_t)k * 64 + c)     * 16 + i];
            s1 += pp[((size_t)k * 64 + c + 1) * 16 + i];
            s2 += pp[((size_t)k * 64 + c + 2) * 16 + i];
            s3 += pp[((size_t)k * 64 + c + 3) * 16 + i];
        }
        sums[k][i] = (s0 + s1) + (s2 + s3);
    }
    __syncthreads();
    if (tid < 10) {
        const int k = tid;
        const float sg = sums[k][0];
        const float inv = 1.0f / sg;
        float mu[4];
        #pragma unroll
        for (int d = 0; d < 4; ++d) mu[d] = sums[k][1 + d] * inv;
        const int pd[10] = {0,0,0,0,1,1,1,2,2,3};
        const int pe[10] = {0,1,2,3,1,2,3,2,3,3};
        float cov[4][4];
        #pragma unroll
        for (int p = 0; p < 10; ++p) {
            float cv = sums[k][5 + p] * inv - mu[pd[p]] * mu[pe[p]];
            cov[pd[p]][pe[p]] = cv;
            cov[pe[p]][pd[p]] = cv;
        }
        #pragma unroll
        for (int d = 0; d < 4; ++d)
            #pragma unroll
            for (int e = 0; e < 4; ++e)
                cov_out[k * 16 + d * 4 + e] = cov[d][e];
        // jitter + Cholesky (4x4, lower)
        #pragma unroll
        for (int d = 0; d < 4; ++d) cov[d][d] += 1e-6f;
        float L00 = sqrtf(cov[0][0]);
        float L10 = cov[1][0] / L00, L20 = cov[2][0] / L00, L30 = cov[3][0] / L00;
        float L11 = sqrtf(cov[1][1] - L10 * L10);
        float L21 = (cov[2][1] - L20 * L10) / L11;
        float L31 = (cov[3][1] - L30 * L10) / L11;
        float L22 = sqrtf(cov[2][2] - L20 * L20 - L21 * L21);
        float L32 = (cov[3][2] - L30 * L20 - L31 * L21) / L22;
        float L33 = sqrtf(cov[3][3] - L30 * L30 - L31 * L31 - L32 * L32);
        float logdet = 2.0f * (logf(L00) + logf(L11) + logf(L22) + logf(L33));
        float phi = sg / (float)N;
        const float log2pi = 1.8378770664093453f;
        float ck = logf(phi) - 0.5f * (logdet + 4.0f * log2pi);
        float* cst = consts + k * 16;
        cst[0] = mu[0]; cst[1] = mu[1]; cst[2] = mu[2]; cst[3] = mu[3];
        cst[4] = L10; cst[5] = L20; cst[6] = L21;
        cst[7] = L30; cst[8] = L31; cst[9] = L32;
        cst[10] = 1.0f / L00; cst[11] = 1.0f / L11;
        cst[12] = 1.0f / L22; cst[13] = 1.0f / L33;
        cst[14] = ck;
    }
}

// ---------------- K4: sample energy ----------------
__global__ __launch_bounds__(256) void energy_k(
    const float* __restrict__ z_out, const float* __restrict__ consts,
    float* __restrict__ e_out) {
    __shared__ float cst[160];
    const int tid = threadIdx.x;
    if (tid < 160) cst[tid] = consts[tid];
    __syncthreads();
    const size_t row = (size_t)blockIdx.x * 256 + tid;
    float4 z = *(const float4*)(z_out + row * 4);
    float lp[10];
    float mx = -1e30f;
    #pragma unroll
    for (int k = 0; k < 10; ++k) {
        const float* q = cst + k * 16;
        float v0 = z.x - q[0], v1 = z.y - q[1], v2 = z.z - q[2], v3 = z.w - q[3];
        float y0 = v0 * q[10];
        float y1 = (v1 - q[4] * y0) * q[11];
        float y2 = (v2 - q[5] * y0 - q[6] * y1) * q[12];
        float y3 = (v3 - q[7] * y0 - q[8] * y1 - q[9] * y2) * q[13];
        float m = y0 * y0 + y1 * y1 + y2 * y2 + y3 * y3;
        lp[k] = q[14] - 0.5f * m;
        mx = fmaxf(mx, lp[k]);
    }
    float s = 0.0f;
    #pragma unroll
    for (int k = 0; k < 10; ++k) s += __expf(lp[k] - mx);
    e_out[row] = -(mx + __logf(s));
}

extern "C" void kernel_launch(void* const* d_in, const int* in_sizes, int n_in,
                              void* d_out, int out_size, void* d_ws, size_t ws_size,
                              hipStream_t stream) {
    const float* x = (const float*)d_in[0];
    const float* W[10];
    const float* B[10];
    for (int i = 0; i < 10; ++i) {
        W[i] = (const float*)d_in[1 + 2 * i];
        B[i] = (const float*)d_in[2 + 2 * i];
    }
    const int N = in_sizes[0] / 120;

    float* out   = (float*)d_out;
    float* e_out = out;                // [N]
    float* g_out = out + (size_t)N;    // [N,10]
    float* z_out = out + (size_t)11 * N; // [N,4]
    float* c_out = out + (size_t)15 * N; // [10,4,4]

    float* ws    = (float*)d_ws;
    float* w2t   = ws;            // 1800
    float* w8t   = ws + 1800;     // 7200
    float* pp    = ws + 9024;     // 10*64*16 = 10240
    float* cst   = ws + 19264;    // 160

    transpose_k<<<32, 256, 0, stream>>>(W[1], w2t, W[7], w8t);

    mlp_k<<<N / TPB, TPB, 0, stream>>>(
        x,
        W[0], B[0],
        B[1],
        W[2], B[2],
        W[3], B[3],
        W[4], B[4],
        W[5], B[5],
        W[6], B[6],
        B[7],
        W[8], B[8],
        W[9], B[9],
        w2t, w8t,
        g_out, z_out);

    stats_k<<<5 * 64, 256, 0, stream>>>(g_out, z_out, pp, N);
    finalize_k<<<1, 256, 0, stream>>>(pp, cst, c_out, N);
    energy_k<<<N / 256, 256, 0, stream>>>(z_out, cst, e_out);
}